// Round 2
// baseline (1608.094 us; speedup 1.0000x reference)
//
#include <hip/hip_runtime.h>
#include <hip/hip_bf16.h>

#define T_ 1024
#define B_ 64
#define H_ 128
#define G_ 512   // 4*H
#define E_ 128
#define V_ 32
#define N_ 8

// ---------------------------------------------------------------------------
// K0: proj[dir][v][g] = b_dir[g] + sum_e W_ih_dir[g][e] * emb[v][e]
// grid 64 = dir*32+v, block 512 (one thread per g)
// ---------------------------------------------------------------------------
__global__ __launch_bounds__(512) void proj_kernel(
    const float* __restrict__ emb,
    const float* __restrict__ Wih_f, const float* __restrict__ b_f,
    const float* __restrict__ Wih_b, const float* __restrict__ b_b,
    float* __restrict__ proj)
{
    int wg  = blockIdx.x;
    int dir = wg >> 5;
    int v   = wg & 31;
    const float* W    = dir ? Wih_b : Wih_f;
    const float* bias = dir ? b_b   : b_f;
    int tid = threadIdx.x;

    __shared__ float4 e_l[E_ / 4];
    if (tid < E_ / 4) e_l[tid] = ((const float4*)(emb + (size_t)v * E_))[tid];
    __syncthreads();

    float acc = bias[tid];
    const float4* wr = (const float4*)(W + (size_t)tid * E_);
#pragma unroll
    for (int k = 0; k < 32; ++k) {
        float4 wv = wr[k], ev = e_l[k];
        acc += wv.x * ev.x;
        acc += wv.y * ev.y;
        acc += wv.z * ev.z;
        acc += wv.w * ev.w;
    }
    proj[((size_t)dir * V_ + v) * G_ + tid] = acc;
}

// ---------------------------------------------------------------------------
// K1: per-(dir,batch) LSTM chain + fused FC partials.
// grid 128 (dir*64+b), block 512.  Thread (j = tid>>2, q = tid&3) holds
// chunk q (32 floats) of all four gate rows {j, 128+j, 256+j, 384+j} of W_hh
// in 128 pinned VGPRs. Per step: 8 ds_read_b128 (rotated, conflict-free) +
// 128 FMA, quad shfl_xor reduce, own-gate activation, quad gather,
// replicated c/h update, ONE barrier (double-buffered h).
// ---------------------------------------------------------------------------
__global__ __launch_bounds__(512, 2) void lstm_kernel(
    const int*   __restrict__ x,
    const float* __restrict__ Whh_f, const float* __restrict__ Whh_b,
    const float* __restrict__ proj,   // [2][V][G]
    const float* __restrict__ fcW,    // [8][256]
    float* __restrict__ part)         // [2][T][B][8]
{
    int wg  = blockIdx.x;
    int dir = wg >> 6;
    int b   = wg & 63;
    int tid = threadIdx.x;
    int j   = tid >> 2;
    int q   = tid & 3;

    __shared__ int    tok_l[T_];
    __shared__ float4 hb4[2][H_ / 4];   // double-buffered h
    __shared__ float  fcw_l[N_][H_];

    for (int s = tid; s < T_; s += 512) tok_l[s] = x[(size_t)b * T_ + s];
    for (int s = tid; s < N_ * H_; s += 512) {
        int n = s >> 7, jj = s & 127;
        fcw_l[n][jj] = fcW[n * 256 + dir * H_ + jj];
    }
    if (tid < H_) ((float*)hb4[0])[tid] = 0.f;

    const float* Whh = dir ? Whh_b : Whh_f;

    // Load W pre-rotated: w4[r][k] = W_hh[r*128+j][ q*32 + ((k+2q)&7)*4 .. +4 )
    // (rotation applied at load so the register index k stays compile-time)
    float4 w4[4][8];
#pragma unroll
    for (int r = 0; r < 4; ++r) {
        const float4* wr = (const float4*)(Whh + (size_t)(r * H_ + j) * H_ + q * 32);
#pragma unroll
        for (int k = 0; k < 8; ++k) w4[r][k] = wr[(k + 2 * q) & 7];
    }
    // Pin W in VGPRs — defeat rematerialization (round-1 VGPR=84 showed the
    // compiler re-loading W from L2 every step: ~1900 cyc/step).
#pragma unroll
    for (int r = 0; r < 4; ++r)
#pragma unroll
        for (int k = 0; k < 8; ++k)
            asm volatile("" : "+v"(w4[r][k].x), "+v"(w4[r][k].y),
                              "+v"(w4[r][k].z), "+v"(w4[r][k].w));

    const float* projd = proj + (size_t)dir * (V_ * G_);
    int gown = q * H_ + j;          // this lane's own gate row
    float c = 0.f;
    __syncthreads();

    int   tok_c = tok_l[dir ? (T_ - 1) : 0];
    float pv_c  = projd[tok_c * G_ + gown];

    int cur = 0;
    for (int t = 0; t < T_; ++t) {
        int tt  = dir ? (T_ - 1 - t) : t;
        int tn  = (t + 1 < T_) ? (t + 1) : t;
        int ttn = dir ? (T_ - 1 - tn) : tn;
        int   tok_n = tok_l[ttn];
        float pv_n  = projd[tok_n * G_ + gown];   // prefetch next step

        const float4* hb = (const float4*)hb4[cur];
        float a0 = 0.f, a1 = 0.f, a2 = 0.f, a3 = 0.f;
#pragma unroll
        for (int k = 0; k < 8; ++k) {
            float4 hv = hb[q * 8 + ((k + 2 * q) & 7)];
            float4 w0 = w4[0][k], w1 = w4[1][k], w2 = w4[2][k], w3 = w4[3][k];
            a0 += w0.x * hv.x; a0 += w0.y * hv.y; a0 += w0.z * hv.z; a0 += w0.w * hv.w;
            a1 += w1.x * hv.x; a1 += w1.y * hv.y; a1 += w1.z * hv.z; a1 += w1.w * hv.w;
            a2 += w2.x * hv.x; a2 += w2.y * hv.y; a2 += w2.z * hv.z; a2 += w2.w * hv.w;
            a3 += w3.x * hv.x; a3 += w3.y * hv.y; a3 += w3.z * hv.z; a3 += w3.w * hv.w;
        }
        // quad reduce (xor tree; all 4 lanes get identical full sums)
        a0 += __shfl_xor(a0, 1); a0 += __shfl_xor(a0, 2);
        a1 += __shfl_xor(a1, 1); a1 += __shfl_xor(a1, 2);
        a2 += __shfl_xor(a2, 1); a2 += __shfl_xor(a2, 2);
        a3 += __shfl_xor(a3, 1); a3 += __shfl_xor(a3, 2);

        // own-gate pre-activation + activation (exact round-1 formulas)
        float tot = (q == 0) ? a0 : (q == 1) ? a1 : (q == 2) ? a2 : a3;
        tot += pv_c;
        float act = (q == 2) ? tanhf(tot) : 1.f / (1.f + expf(-tot));

        // gather the quad's 4 activations
        float b1v = __shfl_xor(act, 1);
        float b2v = __shfl_xor(act, 2);
        float b3v = __shfl_xor(act, 3);
        int m1 = q ^ 1, m2 = q ^ 2, m3 = q ^ 3;
        float gi = (q == 0) ? act : (m1 == 0) ? b1v : (m2 == 0) ? b2v : b3v;
        float gf = (q == 1) ? act : (m1 == 1) ? b1v : (m2 == 1) ? b2v : b3v;
        float gg = (q == 2) ? act : (m1 == 2) ? b1v : (m2 == 2) ? b2v : b3v;
        float go = (q == 3) ? act : (m1 == 3) ? b1v : (m2 == 3) ? b2v : b3v;

        c = gf * c + gi * gg;              // same expression as round 1
        float h = go * tanhf(c);
        if (q == 0) ((float*)hb4[cur ^ 1])[j] = h;
        __syncthreads();                   // single barrier per step

        // fused FC partial on h_t (identical structure to round 1)
        if (tid < H_) {
            int n = tid >> 4, m = tid & 15;
            const float* hl = (const float*)hb4[cur ^ 1];
            float p = 0.f;
#pragma unroll
            for (int s = 0; s < 8; ++s) p += fcw_l[n][m + 16 * s] * hl[m + 16 * s];
            p += __shfl_xor(p, 1);
            p += __shfl_xor(p, 2);
            p += __shfl_xor(p, 4);
            p += __shfl_xor(p, 8);
            if (m == 0) part[(((size_t)dir * T_ + tt) * B_ + b) * N_ + n] = p;
        }
        pv_c = pv_n;
        cur ^= 1;
    }
}

// ---------------------------------------------------------------------------
// K2: Viterbi forward + backtrack. grid 64 (one wave per batch element).
// lane = i*8+j. Forward/argmax/backtrack logic identical to round 1; adds
// double-buffered emission staging with register prefetch of the next chunk.
// ---------------------------------------------------------------------------
__global__ __launch_bounds__(64) void viterbi_kernel(
    const float* __restrict__ part,   // [2][T][B][8]
    const float* __restrict__ fc_b,
    const float* __restrict__ start_t,
    const float* __restrict__ end_t,
    const float* __restrict__ trans,  // [8][8]
    int* __restrict__ out)            // [B][T]
{
    int b = blockIdx.x;
    int l = threadIdx.x;
    int i_of = l >> 3, j_of = l & 7;

    __shared__ float        em_l[2][64][N_];
    __shared__ unsigned int hist_l[T_];

    float tr  = trans[l];        // trans[i_of][j_of]
    float fcb = fc_b[j_of];
    const float* pf = part;
    const float* pb = part + (size_t)T_ * B_ * N_;

    // stage chunk 0
    float ra[8], rb[8];
#pragma unroll
    for (int p = 0; p < 8; ++p) {
        int t = p * 8 + i_of;
        size_t base = ((size_t)t * B_ + b) * N_ + j_of;
        ra[p] = pf[base]; rb[p] = pb[base];
    }
#pragma unroll
    for (int p = 0; p < 8; ++p) em_l[0][p * 8 + i_of][j_of] = (ra[p] + rb[p]) + fcb;
    __syncthreads();

    float score = 0.f;

    for (int cch = 0; cch < 16; ++cch) {
        int cb = cch & 1;
        // prefetch next chunk into registers (hides part[] load latency)
        if (cch + 1 < 16) {
#pragma unroll
            for (int p = 0; p < 8; ++p) {
                int t = (cch + 1) * 64 + p * 8 + i_of;
                size_t base = ((size_t)t * B_ + b) * N_ + j_of;
                ra[p] = pf[base]; rb[p] = pb[base];
            }
        }
        int t0 = cch * 64;
        int qs = 0;
        if (cch == 0) {
            score = start_t[j_of] + em_l[0][0][j_of];
            qs = 1;
        }
        for (int qq = qs; qq < 64; ++qq) {
            int t = t0 + qq;
            float em  = em_l[cb][qq][j_of];
            float s_i = __shfl(score, i_of);     // score[i]
            float v   = (s_i + tr) + em;         // match ref add order
            int   idx = i_of;
#pragma unroll
            for (int d = 8; d <= 32; d <<= 1) {  // argmax over i, first-index ties
                float ov = __shfl_xor(v, d);
                int   oi = __shfl_xor(idx, d);
                if (ov > v || (ov == v && oi < idx)) { v = ov; idx = oi; }
            }
            score = v;
            unsigned int pk = (unsigned int)idx << (3 * j_of);
            pk |= __shfl_xor(pk, 1);
            pk |= __shfl_xor(pk, 2);
            pk |= __shfl_xor(pk, 4);
            if (l == 0) hist_l[t] = pk;
        }
        if (cch + 1 < 16) {
#pragma unroll
            for (int p = 0; p < 8; ++p)
                em_l[cb ^ 1][p * 8 + i_of][j_of] = (ra[p] + rb[p]) + fcb;
        }
        __syncthreads();
    }

    // finalize: score += end_trans; last_tag = argmax_j (first-index ties)
    score += end_t[j_of];
    float v = score;
    int   idx = j_of;
#pragma unroll
    for (int d = 1; d <= 4; d <<= 1) {
        float ov = __shfl_xor(v, d);
        int   oi = __shfl_xor(idx, d);
        if (ov > v || (ov == v && oi < idx)) { v = ov; idx = oi; }
    }
    int tag = idx;
    if (l == 0) out[(size_t)b * T_ + (T_ - 1)] = tag;
    __syncthreads();

    // backtrack: prefetch 16 packed words per block -> serial chain is VALU-only
    for (int t0b = T_ - 16; t0b >= 0; t0b -= 16) {
        unsigned int pk[16];
#pragma unroll
        for (int qq = 0; qq < 16; ++qq) pk[qq] = hist_l[t0b + qq];
#pragma unroll
        for (int qq = 15; qq >= 0; --qq) {
            int t = t0b + qq;
            if (t >= 1) {
                tag = (pk[qq] >> (3 * tag)) & 7;
                if (l == 0) out[(size_t)b * T_ + t - 1] = tag;
            }
        }
    }
}

extern "C" void kernel_launch(void* const* d_in, const int* in_sizes, int n_in,
                              void* d_out, int out_size, void* d_ws, size_t ws_size,
                              hipStream_t stream) {
    (void)in_sizes; (void)n_in; (void)out_size; (void)ws_size;
    const int*   x      = (const int*)  d_in[0];
    const float* emb    = (const float*)d_in[1];
    const float* Wih_f  = (const float*)d_in[2];
    const float* Whh_f  = (const float*)d_in[3];
    const float* b_f    = (const float*)d_in[4];
    const float* Wih_b  = (const float*)d_in[5];
    const float* Whh_b  = (const float*)d_in[6];
    const float* b_b    = (const float*)d_in[7];
    const float* fcW    = (const float*)d_in[8];
    const float* fcb    = (const float*)d_in[9];
    const float* startt = (const float*)d_in[10];
    const float* endt   = (const float*)d_in[11];
    const float* trans  = (const float*)d_in[12];

    float* proj = (float*)d_ws;                    // 2*32*512 floats = 128 KB
    float* part = proj + 2 * V_ * G_;              // 2*1024*64*8 floats = 4 MB
    int*   out  = (int*)d_out;

    proj_kernel<<<64, 512, 0, stream>>>(emb, Wih_f, b_f, Wih_b, b_b, proj);
    lstm_kernel<<<128, 512, 0, stream>>>(x, Whh_f, Whh_b, proj, fcW, part);
    viterbi_kernel<<<64, 64, 0, stream>>>(part, fcb, startt, endt, trans, out);
}

// Round 3
// 1373.243 us; speedup vs baseline: 1.1710x; 1.1710x over previous
//
#include <hip/hip_runtime.h>
#include <hip/hip_bf16.h>

#define T_ 1024
#define B_ 64
#define H_ 128
#define G_ 512   // 4*H
#define E_ 128
#define V_ 32
#define N_ 8

// ---- cross-lane helpers (compile-time controls) ---------------------------
template<int CTRL>
__device__ __forceinline__ float dppf(float x) {
    return __int_as_float(__builtin_amdgcn_update_dpp(0, __float_as_int(x), CTRL, 0xF, 0xF, true));
}
template<int CTRL>
__device__ __forceinline__ int dppi(int x) {
    return __builtin_amdgcn_update_dpp(0, x, CTRL, 0xF, 0xF, true);
}
template<int OFF>
__device__ __forceinline__ float swzf(float x) {
    return __int_as_float(__builtin_amdgcn_ds_swizzle(__float_as_int(x), OFF));
}
template<int OFF>
__device__ __forceinline__ int swzi(int x) {
    return __builtin_amdgcn_ds_swizzle(x, OFF);
}
// DPP ctrl constants: quad_perm[a,b,c,d] = a|b<<2|c<<4|d<<6
#define QP_XOR1 0xB1   // [1,0,3,2]
#define QP_XOR2 0x4E   // [2,3,0,1]
#define QP_BC0  0x00   // [0,0,0,0]
#define QP_BC1  0x55
#define QP_BC2  0xAA
#define QP_BC3  0xFF
#define ROW_ROR8 0x128 // row_ror:8 == lane^8 within 16-row
// ds_swizzle BitMode: (xor<<10)|(or<<5)|and
#define SWZ_XOR4  0x101F
#define SWZ_XOR16 0x401F

// ---------------------------------------------------------------------------
// K0: proj[dir][v][g] = b_dir[g] + sum_e W_ih_dir[g][e] * emb[v][e]
// ---------------------------------------------------------------------------
__global__ __launch_bounds__(512) void proj_kernel(
    const float* __restrict__ emb,
    const float* __restrict__ Wih_f, const float* __restrict__ b_f,
    const float* __restrict__ Wih_b, const float* __restrict__ b_b,
    float* __restrict__ proj)
{
    int wg  = blockIdx.x;
    int dir = wg >> 5;
    int v   = wg & 31;
    const float* W    = dir ? Wih_b : Wih_f;
    const float* bias = dir ? b_b   : b_f;
    int tid = threadIdx.x;

    __shared__ float4 e_l[E_ / 4];
    if (tid < E_ / 4) e_l[tid] = ((const float4*)(emb + (size_t)v * E_))[tid];
    __syncthreads();

    float acc = bias[tid];
    const float4* wr = (const float4*)(W + (size_t)tid * E_);
#pragma unroll
    for (int k = 0; k < 32; ++k) {
        float4 wv = wr[k], ev = e_l[k];
        acc += wv.x * ev.x;
        acc += wv.y * ev.y;
        acc += wv.z * ev.z;
        acc += wv.w * ev.w;
    }
    proj[((size_t)dir * V_ + v) * G_ + tid] = acc;
}

// ---------------------------------------------------------------------------
// K1: per-(dir,batch) LSTM chain + fused FC.
// grid 128, block 512. Thread (j=tid>>2, q=tid&3) holds chunk q (32 floats)
// of all 4 gate rows of j in 128 VGPRs (amdgpu_waves_per_eu(2,2) -> 256-VGPR
// cap so the allocator keeps them resident; round-2's VGPR=88 proved spill).
// Quad reduce + gate gather via DPP quad_perm (VALU, not DS).
// FC spread over all 8 waves: wave n computes logit n (2 FMA + butterfly).
// ---------------------------------------------------------------------------
__global__ __launch_bounds__(512)
__attribute__((amdgpu_waves_per_eu(2, 2)))
void lstm_kernel(
    const int*   __restrict__ x,
    const float* __restrict__ Whh_f, const float* __restrict__ Whh_b,
    const float* __restrict__ proj,   // [2][V][G]
    const float* __restrict__ fcW,    // [8][256]
    float* __restrict__ part)         // [2][T][B][8]
{
    int wg  = blockIdx.x;
    int dir = wg >> 6;
    int b   = wg & 63;
    int tid = threadIdx.x;
    int j   = tid >> 2;
    int q   = tid & 3;
    int nw  = tid >> 6;     // FC output index (wave id)
    int e   = tid & 63;     // FC element pair index

    __shared__ int    tok_l[T_];
    __shared__ float4 hb4[2][H_ / 4];   // double-buffered h

    for (int s = tid; s < T_; s += 512) tok_l[s] = x[(size_t)b * T_ + s];
    if (tid < H_) ((float*)hb4[0])[tid] = 0.f;

    float fw0 = fcW[nw * 256 + dir * H_ + 2 * e];
    float fw1 = fcW[nw * 256 + dir * H_ + 2 * e + 1];

    const float* Whh = dir ? Whh_b : Whh_f;

    // w4[r][k] = W_hh[r*128+j][ q*32 + ((k+2q)&7)*4 .. +4 )  (rotation at load,
    // register index k compile-time; rotation makes the 4 quad addresses
    // bank-disjoint on the LDS read side)
    float4 w4[4][8];
#pragma unroll
    for (int r = 0; r < 4; ++r) {
        const float4* wr = (const float4*)(Whh + (size_t)(r * H_ + j) * H_ + q * 32);
#pragma unroll
        for (int k = 0; k < 8; ++k) w4[r][k] = wr[(k + 2 * q) & 7];
    }
#pragma unroll
    for (int r = 0; r < 4; ++r)
#pragma unroll
        for (int k = 0; k < 8; ++k)
            asm volatile("" : "+v"(w4[r][k].x), "+v"(w4[r][k].y),
                              "+v"(w4[r][k].z), "+v"(w4[r][k].w));
    asm volatile("" : "+v"(fw0), "+v"(fw1));

    const float* projd = proj + (size_t)dir * (V_ * G_);
    int gown = q * H_ + j;          // own gate row in proj
    float c = 0.f;
    __syncthreads();

    float pv_c = projd[tok_l[dir ? (T_ - 1) : 0] * G_ + gown];

    int cur = 0;
    for (int t = 0; t < T_; ++t) {
        int tt = dir ? (T_ - 1 - t) : t;
        int tn = (t + 1 < T_) ? (t + 1) : t;
        float pv_n = projd[tok_l[dir ? (T_ - 1 - tn) : tn] * G_ + gown];

        const float4* hb = (const float4*)hb4[cur];
        float a0 = 0.f, a1 = 0.f, a2 = 0.f, a3 = 0.f;
#pragma unroll
        for (int k = 0; k < 8; ++k) {
            float4 hv = hb[q * 8 + ((k + 2 * q) & 7)];
            float4 w0 = w4[0][k], w1 = w4[1][k], w2 = w4[2][k], w3 = w4[3][k];
            a0 += w0.x * hv.x; a0 += w0.y * hv.y; a0 += w0.z * hv.z; a0 += w0.w * hv.w;
            a1 += w1.x * hv.x; a1 += w1.y * hv.y; a1 += w1.z * hv.z; a1 += w1.w * hv.w;
            a2 += w2.x * hv.x; a2 += w2.y * hv.y; a2 += w2.z * hv.z; a2 += w2.w * hv.w;
            a3 += w3.x * hv.x; a3 += w3.y * hv.y; a3 += w3.z * hv.z; a3 += w3.w * hv.w;
        }
        // quad reduce via DPP (same math as shfl_xor 1,2 — bit-identical)
        a0 += dppf<QP_XOR1>(a0); a0 += dppf<QP_XOR2>(a0);
        a1 += dppf<QP_XOR1>(a1); a1 += dppf<QP_XOR2>(a1);
        a2 += dppf<QP_XOR1>(a2); a2 += dppf<QP_XOR2>(a2);
        a3 += dppf<QP_XOR1>(a3); a3 += dppf<QP_XOR2>(a3);

        float tot = (q == 0) ? a0 : (q == 1) ? a1 : (q == 2) ? a2 : a3;
        tot += pv_c;
        float act = (q == 2) ? tanhf(tot) : 1.f / (1.f + expf(-tot));

        // gather quad activations via DPP broadcasts (lane0..3 of quad)
        float gi = dppf<QP_BC0>(act);
        float gf = dppf<QP_BC1>(act);
        float gg = dppf<QP_BC2>(act);
        float go = dppf<QP_BC3>(act);

        c = gf * c + gi * gg;
        float h = go * tanhf(c);
        if (q == 0) ((float*)hb4[cur ^ 1])[j] = h;
        __syncthreads();                   // single barrier per step

        // FC: wave nw computes logit nw; each lane dots 2 h elements
        float2 h2 = ((const float2*)hb4[cur ^ 1])[e];
        float p = fw0 * h2.x + fw1 * h2.y;
        p += dppf<QP_XOR1>(p);             // xor1
        p += dppf<QP_XOR2>(p);             // xor2
        p += swzf<SWZ_XOR4>(p);            // xor4
        p += dppf<ROW_ROR8>(p);            // xor8
        p += swzf<SWZ_XOR16>(p);           // xor16
        float psum = p + __int_as_float(__builtin_amdgcn_readlane(__float_as_int(p), 32));
        if (e == 0) part[(((size_t)dir * T_ + tt) * B_ + b) * N_ + nw] = psum;

        pv_c = pv_n;
        cur ^= 1;
    }
}

// ---------------------------------------------------------------------------
// K2: Viterbi. grid 64, block 64 (one wave per batch element).
// Alternating layouts: after transition t the score lives j-major (lane&7)
// for even t, j-in-high-bits (lane>>3) for odd t -> NO score shuffle per step.
// Emissions double-buffered in registers (global loads one sub-block ahead).
// Tournament (max, min-index tie) is order-free, so level order is free.
// ---------------------------------------------------------------------------
__global__ __launch_bounds__(64) void viterbi_kernel(
    const float* __restrict__ part,   // [2][T][B][8]
    const float* __restrict__ fc_b,
    const float* __restrict__ start_t,
    const float* __restrict__ end_t,
    const float* __restrict__ trans,  // [8][8]
    int* __restrict__ out)            // [B][T]
{
    int b = blockIdx.x;
    int l = threadIdx.x;
    int lo = l & 7, hi = l >> 3;

    __shared__ unsigned int hist_l[T_];

    float trA  = trans[lo * 8 + hi];   // style A: i=lo, j=hi
    float trB  = trans[hi * 8 + lo];   // style B: i=hi, j=lo
    float fcbA = fc_b[hi];
    float fcbB = fc_b[lo];
    const float* pf = part;
    const float* pb = part + (size_t)T_ * B_ * N_;

#define TSEL(ov, oi) { if ((ov) > v || ((ov) == v && (oi) < idx)) { v = (ov); idx = (oi); } }

    // style A (odd t): input j-major, i=lo; reduce lanes over low bits; out high-major
#define VSTEPA(emval, tcur) { \
    float v = (score + trA) + (emval); int idx = lo; \
    { float ov = dppf<QP_XOR1>(v); int oi = dppi<QP_XOR1>(idx); TSEL(ov, oi) } \
    { float ov = dppf<QP_XOR2>(v); int oi = dppi<QP_XOR2>(idx); TSEL(ov, oi) } \
    { float ov = swzf<SWZ_XOR4>(v); int oi = swzi<SWZ_XOR4>(idx); TSEL(ov, oi) } \
    score = v; \
    unsigned pk = 0; \
    _Pragma("unroll") \
    for (int jj = 0; jj < 8; ++jj) \
        pk |= (unsigned)(__builtin_amdgcn_readlane(idx, 8 * jj) & 7) << (3 * jj); \
    if (l == 0) hist_l[tcur] = pk; }

    // style B (even t>0): input high-major, i=hi; reduce over high bits; out j-major
#define VSTEPB(emval, tcur) { \
    float v = (score + trB) + (emval); int idx = hi; \
    { float ov = dppf<ROW_ROR8>(v); int oi = dppi<ROW_ROR8>(idx); TSEL(ov, oi) } \
    { float ov = swzf<SWZ_XOR16>(v); int oi = swzi<SWZ_XOR16>(idx); TSEL(ov, oi) } \
    { float ov = __shfl_xor(v, 32); int oi = __shfl_xor(idx, 32); TSEL(ov, oi) } \
    score = v; \
    unsigned pk = 0; \
    _Pragma("unroll") \
    for (int jj = 0; jj < 8; ++jj) \
        pk |= (unsigned)(__builtin_amdgcn_readlane(idx, jj) & 7) << (3 * jj); \
    if (l == 0) hist_l[tcur] = pk; }

    // sub-block loads: t0 = ss*8 (even), so parity(t) == parity(p)
#define LOADSUB(dst, ss) { \
    int t0_ = (ss) * 8; \
    _Pragma("unroll") \
    for (int p = 0; p < 8; ++p) { \
        int t_ = t0_ + p; \
        int jsel = (p & 1) ? hi : lo; \
        float fcbs = (p & 1) ? fcbA : fcbB; \
        size_t base = ((size_t)t_ * B_ + b) * N_ + jsel; \
        dst[p] = (pf[base] + pb[base]) + fcbs; } }

#define PROC8(arr, t0_) { \
    VSTEPB(arr[0], (t0_) + 0) VSTEPA(arr[1], (t0_) + 1) \
    VSTEPB(arr[2], (t0_) + 2) VSTEPA(arr[3], (t0_) + 3) \
    VSTEPB(arr[4], (t0_) + 4) VSTEPA(arr[5], (t0_) + 5) \
    VSTEPB(arr[6], (t0_) + 6) VSTEPA(arr[7], (t0_) + 7) }

    float emA[8], emB[8];
    float score;

    LOADSUB(emA, 0)
    LOADSUB(emB, 1)
    // sub-block 0: init (t=0, j-major) + transitions t=1..7 (A,B,A,B,A,B,A)
    score = start_t[lo] + emA[0];
    VSTEPA(emA[1], 1) VSTEPB(emA[2], 2) VSTEPA(emA[3], 3) VSTEPB(emA[4], 4)
    VSTEPA(emA[5], 5) VSTEPB(emA[6], 6) VSTEPA(emA[7], 7)

    for (int s = 1; s < 127; s += 2) {
        LOADSUB(emA, s + 1)
        PROC8(emB, s * 8)
        LOADSUB(emB, s + 2)
        PROC8(emA, (s + 1) * 8)
    }
    PROC8(emB, 127 * 8)

    // final: t=1023 odd -> score high-major (lane holds score[hi])
    score += end_t[hi];
    int tag;
    {
        float v = score; int idx = hi;
        { float ov = dppf<ROW_ROR8>(v); int oi = dppi<ROW_ROR8>(idx); TSEL(ov, oi) }
        { float ov = swzf<SWZ_XOR16>(v); int oi = swzi<SWZ_XOR16>(idx); TSEL(ov, oi) }
        { float ov = __shfl_xor(v, 32); int oi = __shfl_xor(idx, 32); TSEL(ov, oi) }
        tag = idx;
    }
    if (l == 0) out[(size_t)b * T_ + (T_ - 1)] = tag;
    __syncthreads();

    // backtrack: prefetch 16 packed words per block -> serial chain is VALU-only
    for (int t0b = T_ - 16; t0b >= 0; t0b -= 16) {
        unsigned int pk[16];
#pragma unroll
        for (int qq = 0; qq < 16; ++qq) pk[qq] = hist_l[t0b + qq];
#pragma unroll
        for (int qq = 15; qq >= 0; --qq) {
            int t = t0b + qq;
            if (t >= 1) {
                tag = (pk[qq] >> (3 * tag)) & 7;
                if (l == 0) out[(size_t)b * T_ + t - 1] = tag;
            }
        }
    }
#undef TSEL
#undef VSTEPA
#undef VSTEPB
#undef LOADSUB
#undef PROC8
}

extern "C" void kernel_launch(void* const* d_in, const int* in_sizes, int n_in,
                              void* d_out, int out_size, void* d_ws, size_t ws_size,
                              hipStream_t stream) {
    (void)in_sizes; (void)n_in; (void)out_size; (void)ws_size;
    const int*   x      = (const int*)  d_in[0];
    const float* emb    = (const float*)d_in[1];
    const float* Wih_f  = (const float*)d_in[2];
    const float* Whh_f  = (const float*)d_in[3];
    const float* b_f    = (const float*)d_in[4];
    const float* Wih_b  = (const float*)d_in[5];
    const float* Whh_b  = (const float*)d_in[6];
    const float* b_b    = (const float*)d_in[7];
    const float* fcW    = (const float*)d_in[8];
    const float* fcb    = (const float*)d_in[9];
    const float* startt = (const float*)d_in[10];
    const float* endt   = (const float*)d_in[11];
    const float* trans  = (const float*)d_in[12];

    float* proj = (float*)d_ws;                    // 2*32*512 floats = 128 KB
    float* part = proj + 2 * V_ * G_;              // 2*1024*64*8 floats = 4 MB
    int*   out  = (int*)d_out;

    proj_kernel<<<64, 512, 0, stream>>>(emb, Wih_f, b_f, Wih_b, b_b, proj);
    lstm_kernel<<<128, 512, 0, stream>>>(x, Whh_f, Whh_b, proj, fcW, part);
    viterbi_kernel<<<64, 64, 0, stream>>>(part, fcb, startt, endt, trans, out);
}

// Round 6
// 1364.601 us; speedup vs baseline: 1.1784x; 1.0063x over previous
//
#include <hip/hip_runtime.h>
#include <hip/hip_bf16.h>

#define T_ 1024
#define B_ 64
#define H_ 128
#define G_ 512   // 4*H
#define E_ 128
#define V_ 32
#define N_ 8

// ---- cross-lane helpers (compile-time controls) ---------------------------
template<int CTRL>
__device__ __forceinline__ float dppf(float x) {
    return __int_as_float(__builtin_amdgcn_update_dpp(0, __float_as_int(x), CTRL, 0xF, 0xF, true));
}
template<int CTRL>
__device__ __forceinline__ int dppi(int x) {
    return __builtin_amdgcn_update_dpp(0, x, CTRL, 0xF, 0xF, true);
}
template<int OFF>
__device__ __forceinline__ float swzf(float x) {
    return __int_as_float(__builtin_amdgcn_ds_swizzle(__float_as_int(x), OFF));
}
template<int OFF>
__device__ __forceinline__ int swzi(int x) {
    return __builtin_amdgcn_ds_swizzle(x, OFF);
}
// DPP ctrl constants: quad_perm[a,b,c,d] = a|b<<2|c<<4|d<<6
#define QP_XOR1 0xB1   // [1,0,3,2]
#define QP_XOR2 0x4E   // [2,3,0,1]
#define QP_BC0  0x00
#define QP_BC1  0x55
#define QP_BC2  0xAA
#define QP_BC3  0xFF
#define ROW_ROR8 0x128 // row_ror:8 == xor8 within 16-row (for sums)
// ds_swizzle BitMode: (xor<<10)|(or<<5)|and
#define SWZ_XOR4  0x101F
#define SWZ_XOR16 0x401F

// ---------------------------------------------------------------------------
// K0: proj[dir][v][g] = b_dir[g] + sum_e W_ih_dir[g][e] * emb[v][e]
// ---------------------------------------------------------------------------
__global__ __launch_bounds__(512) void proj_kernel(
    const float* __restrict__ emb,
    const float* __restrict__ Wih_f, const float* __restrict__ b_f,
    const float* __restrict__ Wih_b, const float* __restrict__ b_b,
    float* __restrict__ proj)
{
    int wg  = blockIdx.x;
    int dir = wg >> 5;
    int v   = wg & 31;
    const float* W    = dir ? Wih_b : Wih_f;
    const float* bias = dir ? b_b   : b_f;
    int tid = threadIdx.x;

    __shared__ float4 e_l[E_ / 4];
    if (tid < E_ / 4) e_l[tid] = ((const float4*)(emb + (size_t)v * E_))[tid];
    __syncthreads();

    float acc = bias[tid];
    const float4* wr = (const float4*)(W + (size_t)tid * E_);
#pragma unroll
    for (int k = 0; k < 32; ++k) {
        float4 wv = wr[k], ev = e_l[k];
        acc += wv.x * ev.x;
        acc += wv.y * ev.y;
        acc += wv.z * ev.z;
        acc += wv.w * ev.w;
    }
    proj[((size_t)dir * V_ + v) * G_ + tid] = acc;
}

// ---------------------------------------------------------------------------
// K1: per-(dir,batch) LSTM chain + fused FC.  [round-3 math + LDS union only]
// grid 128, block 512. Thread (j=tid>>2, q=tid&3) holds chunk q (32 floats)
// of all 4 gate rows of j in 128 VGPRs. 84KB static LDS forces 1 block/CU
// at COMPILE time -> 2 waves/EU -> 256-VGPR budget -> no spill incentive.
// ---------------------------------------------------------------------------
__global__ __launch_bounds__(512)
__attribute__((amdgpu_waves_per_eu(2, 2)))
void lstm_kernel(
    const int*   __restrict__ x,
    const float* __restrict__ Whh_f, const float* __restrict__ Whh_b,
    const float* __restrict__ proj,   // [2][V][G]
    const float* __restrict__ fcW,    // [8][256]
    float* __restrict__ part)         // [2][T][B][8]
{
    int wg  = blockIdx.x;
    int dir = wg >> 6;
    int b   = wg & 63;
    int tid = threadIdx.x;
    int j   = tid >> 2;
    int q   = tid & 3;
    int nw  = tid >> 6;     // FC output index (wave id)
    int e   = tid & 63;     // FC element pair index

    // tok + 83KB pad union: forces 1 block/CU at compile time (see above).
    __shared__ union { int tok[T_]; char pad[83 * 1024]; } tu;
    __shared__ float4 hb4[2][H_ / 4];   // double-buffered h

    for (int s = tid; s < T_; s += 512) tu.tok[s] = x[(size_t)b * T_ + s];
    if (tid < H_) ((float*)hb4[0])[tid] = 0.f;

    float fw0 = fcW[nw * 256 + dir * H_ + 2 * e];
    float fw1 = fcW[nw * 256 + dir * H_ + 2 * e + 1];

    const float* Whh = dir ? Whh_b : Whh_f;

    // w4[r][k] = W_hh[r*128+j][ q*32 + ((k+2q)&7)*4 .. +4 )
    float4 w4[4][8];
#pragma unroll
    for (int r = 0; r < 4; ++r) {
        const float4* wr = (const float4*)(Whh + (size_t)(r * H_ + j) * H_ + q * 32);
#pragma unroll
        for (int k = 0; k < 8; ++k) w4[r][k] = wr[(k + 2 * q) & 7];
    }
#pragma unroll
    for (int r = 0; r < 4; ++r)
#pragma unroll
        for (int k = 0; k < 8; ++k)
            asm volatile("" : "+v"(w4[r][k].x), "+v"(w4[r][k].y),
                              "+v"(w4[r][k].z), "+v"(w4[r][k].w));
    asm volatile("" : "+v"(fw0), "+v"(fw1));

    const float* projd = proj + (size_t)dir * (V_ * G_);
    int gown = q * H_ + j;          // own gate row in proj
    float c = 0.f;
    __syncthreads();

    float pv_c = projd[tu.tok[dir ? (T_ - 1) : 0] * G_ + gown];

    int cur = 0;
    for (int t = 0; t < T_; ++t) {
        int tt = dir ? (T_ - 1 - t) : t;
        int tn = (t + 1 < T_) ? (t + 1) : t;
        float pv_n = projd[tu.tok[dir ? (T_ - 1 - tn) : tn] * G_ + gown];

        const float4* hb = (const float4*)hb4[cur];
        float a0 = 0.f, a1 = 0.f, a2 = 0.f, a3 = 0.f;
#pragma unroll
        for (int k = 0; k < 8; ++k) {
            float4 hv = hb[q * 8 + ((k + 2 * q) & 7)];
            float4 w0 = w4[0][k], w1 = w4[1][k], w2 = w4[2][k], w3 = w4[3][k];
            a0 += w0.x * hv.x; a0 += w0.y * hv.y; a0 += w0.z * hv.z; a0 += w0.w * hv.w;
            a1 += w1.x * hv.x; a1 += w1.y * hv.y; a1 += w1.z * hv.z; a1 += w1.w * hv.w;
            a2 += w2.x * hv.x; a2 += w2.y * hv.y; a2 += w2.z * hv.z; a2 += w2.w * hv.w;
            a3 += w3.x * hv.x; a3 += w3.y * hv.y; a3 += w3.z * hv.z; a3 += w3.w * hv.w;
        }
        // quad reduce via DPP (bit-identical to shfl_xor 1,2)
        a0 += dppf<QP_XOR1>(a0); a0 += dppf<QP_XOR2>(a0);
        a1 += dppf<QP_XOR1>(a1); a1 += dppf<QP_XOR2>(a1);
        a2 += dppf<QP_XOR1>(a2); a2 += dppf<QP_XOR2>(a2);
        a3 += dppf<QP_XOR1>(a3); a3 += dppf<QP_XOR2>(a3);

        float tot = (q == 0) ? a0 : (q == 1) ? a1 : (q == 2) ? a2 : a3;
        tot += pv_c;
        float act = (q == 2) ? tanhf(tot) : 1.f / (1.f + expf(-tot));

        // gather quad activations via DPP broadcasts
        float gi = dppf<QP_BC0>(act);
        float gf = dppf<QP_BC1>(act);
        float gg = dppf<QP_BC2>(act);
        float go = dppf<QP_BC3>(act);

        c = gf * c + gi * gg;
        float h = go * tanhf(c);
        if (q == 0) ((float*)hb4[cur ^ 1])[j] = h;
        __syncthreads();                   // single barrier per step

        // FC: wave nw computes logit nw; each lane dots 2 h elements
        float2 h2 = ((const float2*)hb4[cur ^ 1])[e];
        float p = fw0 * h2.x + fw1 * h2.y;
        p += dppf<QP_XOR1>(p);
        p += dppf<QP_XOR2>(p);
        p += swzf<SWZ_XOR4>(p);
        p += dppf<ROW_ROR8>(p);
        p += swzf<SWZ_XOR16>(p);
        float psum = p + __int_as_float(__builtin_amdgcn_readlane(__float_as_int(p), 32));
        if (e == 0) part[(((size_t)dir * T_ + tt) * B_ + b) * N_ + nw] = psum;

        pv_c = pv_n;
        cur ^= 1;
    }
}

// ---------------------------------------------------------------------------
// K2: Viterbi — round-3 alternating-layout version VERBATIM (passed, absmax 0).
// grid 64, block 64. Score alternates j-major (even t) / high-major (odd t)
// so no per-step score transpose. Emissions double-buffered in registers.
// ---------------------------------------------------------------------------
__global__ __launch_bounds__(64) void viterbi_kernel(
    const float* __restrict__ part,   // [2][T][B][8]
    const float* __restrict__ fc_b,
    const float* __restrict__ start_t,
    const float* __restrict__ end_t,
    const float* __restrict__ trans,  // [8][8]
    int* __restrict__ out)            // [B][T]
{
    int b = blockIdx.x;
    int l = threadIdx.x;
    int lo = l & 7, hi = l >> 3;

    __shared__ unsigned int hist_l[T_];

    float trA  = trans[lo * 8 + hi];   // style A: i=lo, j=hi
    float trB  = trans[hi * 8 + lo];   // style B: i=hi, j=lo
    float fcbA = fc_b[hi];
    float fcbB = fc_b[lo];
    const float* pf = part;
    const float* pb = part + (size_t)T_ * B_ * N_;

#define TSEL(ov, oi) { if ((ov) > v || ((ov) == v && (oi) < idx)) { v = (ov); idx = (oi); } }

    // style A (odd t): input j-major, i=lo; reduce lanes over low bits; out high-major
#define VSTEPA(emval, tcur) { \
    float v = (score + trA) + (emval); int idx = lo; \
    { float ov = dppf<QP_XOR1>(v); int oi = dppi<QP_XOR1>(idx); TSEL(ov, oi) } \
    { float ov = dppf<QP_XOR2>(v); int oi = dppi<QP_XOR2>(idx); TSEL(ov, oi) } \
    { float ov = swzf<SWZ_XOR4>(v); int oi = swzi<SWZ_XOR4>(idx); TSEL(ov, oi) } \
    score = v; \
    unsigned pk = 0; \
    _Pragma("unroll") \
    for (int jj = 0; jj < 8; ++jj) \
        pk |= (unsigned)(__builtin_amdgcn_readlane(idx, 8 * jj) & 7) << (3 * jj); \
    if (l == 0) hist_l[tcur] = pk; }

    // style B (even t>0): input high-major, i=hi; reduce over high bits; out j-major
#define VSTEPB(emval, tcur) { \
    float v = (score + trB) + (emval); int idx = hi; \
    { float ov = dppf<ROW_ROR8>(v); int oi = dppi<ROW_ROR8>(idx); TSEL(ov, oi) } \
    { float ov = swzf<SWZ_XOR16>(v); int oi = swzi<SWZ_XOR16>(idx); TSEL(ov, oi) } \
    { float ov = __shfl_xor(v, 32); int oi = __shfl_xor(idx, 32); TSEL(ov, oi) } \
    score = v; \
    unsigned pk = 0; \
    _Pragma("unroll") \
    for (int jj = 0; jj < 8; ++jj) \
        pk |= (unsigned)(__builtin_amdgcn_readlane(idx, jj) & 7) << (3 * jj); \
    if (l == 0) hist_l[tcur] = pk; }

    // sub-block loads: t0 = ss*8 (even), so parity(t) == parity(p)
#define LOADSUB(dst, ss) { \
    int t0_ = (ss) * 8; \
    _Pragma("unroll") \
    for (int p = 0; p < 8; ++p) { \
        int t_ = t0_ + p; \
        int jsel = (p & 1) ? hi : lo; \
        float fcbs = (p & 1) ? fcbA : fcbB; \
        size_t base = ((size_t)t_ * B_ + b) * N_ + jsel; \
        dst[p] = (pf[base] + pb[base]) + fcbs; } }

#define PROC8(arr, t0_) { \
    VSTEPB(arr[0], (t0_) + 0) VSTEPA(arr[1], (t0_) + 1) \
    VSTEPB(arr[2], (t0_) + 2) VSTEPA(arr[3], (t0_) + 3) \
    VSTEPB(arr[4], (t0_) + 4) VSTEPA(arr[5], (t0_) + 5) \
    VSTEPB(arr[6], (t0_) + 6) VSTEPA(arr[7], (t0_) + 7) }

    float emA[8], emB[8];
    float score;

    LOADSUB(emA, 0)
    LOADSUB(emB, 1)
    // sub-block 0: init (t=0, j-major) + transitions t=1..7 (A,B,A,B,A,B,A)
    score = start_t[lo] + emA[0];
    VSTEPA(emA[1], 1) VSTEPB(emA[2], 2) VSTEPA(emA[3], 3) VSTEPB(emA[4], 4)
    VSTEPA(emA[5], 5) VSTEPB(emA[6], 6) VSTEPA(emA[7], 7)

    for (int s = 1; s < 127; s += 2) {
        LOADSUB(emA, s + 1)
        PROC8(emB, s * 8)
        LOADSUB(emB, s + 2)
        PROC8(emA, (s + 1) * 8)
    }
    PROC8(emB, 127 * 8)

    // final: t=1023 odd -> score high-major (lane holds score[hi])
    score += end_t[hi];
    int tag;
    {
        float v = score; int idx = hi;
        { float ov = dppf<ROW_ROR8>(v); int oi = dppi<ROW_ROR8>(idx); TSEL(ov, oi) }
        { float ov = swzf<SWZ_XOR16>(v); int oi = swzi<SWZ_XOR16>(idx); TSEL(ov, oi) }
        { float ov = __shfl_xor(v, 32); int oi = __shfl_xor(idx, 32); TSEL(ov, oi) }
        tag = idx;
    }
    if (l == 0) out[(size_t)b * T_ + (T_ - 1)] = tag;
    __syncthreads();

    // backtrack: prefetch 16 packed words per block -> serial chain is VALU-only
    for (int t0b = T_ - 16; t0b >= 0; t0b -= 16) {
        unsigned int pk[16];
#pragma unroll
        for (int qq = 0; qq < 16; ++qq) pk[qq] = hist_l[t0b + qq];
#pragma unroll
        for (int qq = 15; qq >= 0; --qq) {
            int t = t0b + qq;
            if (t >= 1) {
                tag = (pk[qq] >> (3 * tag)) & 7;
                if (l == 0) out[(size_t)b * T_ + t - 1] = tag;
            }
        }
    }
#undef TSEL
#undef VSTEPA
#undef VSTEPB
#undef LOADSUB
#undef PROC8
}

extern "C" void kernel_launch(void* const* d_in, const int* in_sizes, int n_in,
                              void* d_out, int out_size, void* d_ws, size_t ws_size,
                              hipStream_t stream) {
    (void)in_sizes; (void)n_in; (void)out_size; (void)ws_size;
    const int*   x      = (const int*)  d_in[0];
    const float* emb    = (const float*)d_in[1];
    const float* Wih_f  = (const float*)d_in[2];
    const float* Whh_f  = (const float*)d_in[3];
    const float* b_f    = (const float*)d_in[4];
    const float* Wih_b  = (const float*)d_in[5];
    const float* Whh_b  = (const float*)d_in[6];
    const float* b_b    = (const float*)d_in[7];
    const float* fcW    = (const float*)d_in[8];
    const float* fcb    = (const float*)d_in[9];
    const float* startt = (const float*)d_in[10];
    const float* endt   = (const float*)d_in[11];
    const float* trans  = (const float*)d_in[12];

    float* proj = (float*)d_ws;                    // 2*32*512 floats = 128 KB
    float* part = proj + 2 * V_ * G_;              // 2*1024*64*8 floats = 4 MB
    int*   out  = (int*)d_out;

    proj_kernel<<<64, 512, 0, stream>>>(emb, Wih_f, b_f, Wih_b, b_b, proj);
    lstm_kernel<<<128, 512, 0, stream>>>(x, Whh_f, Whh_b, proj, fcW, part);
    viterbi_kernel<<<64, 64, 0, stream>>>(part, fcb, startt, endt, trans, out);
}

// Round 7
// 1311.553 us; speedup vs baseline: 1.2261x; 1.0404x over previous
//
#include <hip/hip_runtime.h>
#include <hip/hip_bf16.h>

#define T_ 1024
#define B_ 64
#define H_ 128
#define G_ 512   // 4*H
#define E_ 128
#define V_ 32
#define N_ 8

// ---- cross-lane helpers (compile-time controls) ---------------------------
template<int CTRL>
__device__ __forceinline__ float dppf(float x) {
    return __int_as_float(__builtin_amdgcn_update_dpp(0, __float_as_int(x), CTRL, 0xF, 0xF, true));
}
template<int CTRL>
__device__ __forceinline__ int dppi(int x) {
    return __builtin_amdgcn_update_dpp(0, x, CTRL, 0xF, 0xF, true);
}
template<int OFF>
__device__ __forceinline__ float swzf(float x) {
    return __int_as_float(__builtin_amdgcn_ds_swizzle(__float_as_int(x), OFF));
}
template<int OFF>
__device__ __forceinline__ int swzi(int x) {
    return __builtin_amdgcn_ds_swizzle(x, OFF);
}
// DPP ctrl constants: quad_perm[a,b,c,d] = a|b<<2|c<<4|d<<6
#define QP_XOR1 0xB1   // [1,0,3,2]
#define QP_XOR2 0x4E   // [2,3,0,1]
#define QP_BC0  0x00
#define QP_BC1  0x55
#define QP_BC2  0xAA
#define QP_BC3  0xFF
#define ROW_ROR8 0x128 // row_ror:8 == xor8 within 16-row (for sums)
// ds_swizzle BitMode: (xor<<10)|(or<<5)|and
#define SWZ_XOR4  0x101F
#define SWZ_XOR16 0x401F

// ---------------------------------------------------------------------------
// K0: proj[dir][v][g] = b_dir[g] + sum_e W_ih_dir[g][e] * emb[v][e]
// ---------------------------------------------------------------------------
__global__ __launch_bounds__(512) void proj_kernel(
    const float* __restrict__ emb,
    const float* __restrict__ Wih_f, const float* __restrict__ b_f,
    const float* __restrict__ Wih_b, const float* __restrict__ b_b,
    float* __restrict__ proj)
{
    int wg  = blockIdx.x;
    int dir = wg >> 5;
    int v   = wg & 31;
    const float* W    = dir ? Wih_b : Wih_f;
    const float* bias = dir ? b_b   : b_f;
    int tid = threadIdx.x;

    __shared__ float4 e_l[E_ / 4];
    if (tid < E_ / 4) e_l[tid] = ((const float4*)(emb + (size_t)v * E_))[tid];
    __syncthreads();

    float acc = bias[tid];
    const float4* wr = (const float4*)(W + (size_t)tid * E_);
#pragma unroll
    for (int k = 0; k < 32; ++k) {
        float4 wv = wr[k], ev = e_l[k];
        acc += wv.x * ev.x;
        acc += wv.y * ev.y;
        acc += wv.z * ev.z;
        acc += wv.w * ev.w;
    }
    proj[((size_t)dir * V_ + v) * G_ + tid] = acc;
}

// ---------------------------------------------------------------------------
// K1: per-(dir,batch) LSTM chain + fused FC.  [round-6 math; W init path
// changed: global -> LDS stage -> registers, with overwrite-kill]
//
// Why: rounds 1-6 showed the allocator never keeps the 128 W-floats/thread
// resident (VGPR=84/88) regardless of occupancy attributes — the const
// __restrict__ global loads are REMATERIALIZABLE, so LLVM replays them
// in-loop instead of spilling (34 GB of L2 reads = measured 1.08 ms at the
// 32 TB/s L2 roofline). Staging each gate slice through LDS and then
// OVERWRITING that LDS region with the next gate makes the ds_read results
// impossible to rematerialize -> values must live in VGPRs (or scratch,
// which is no worse than today). Gate 3's region is never overwritten, so
// its per-step re-read (if the compiler chooses it) is legal and LDS-cheap.
// 80KB+ static LDS still forces 1 block/CU -> 2 waves/SIMD -> 256-reg cap.
// ---------------------------------------------------------------------------
__global__ __launch_bounds__(512)
__attribute__((amdgpu_waves_per_eu(2, 2)))
void lstm_kernel(
    const int*   __restrict__ x,
    const float* __restrict__ Whh_f, const float* __restrict__ Whh_b,
    const float* __restrict__ proj,   // [2][V][G]
    const float* __restrict__ fcW,    // [8][256]
    float* __restrict__ part)         // [2][T][B][8]
{
    int wg  = blockIdx.x;
    int dir = wg >> 6;
    int b   = wg & 63;
    int tid = threadIdx.x;
    int j   = tid >> 2;
    int q   = tid & 3;
    int nw  = tid >> 6;     // FC output index (wave id)
    int e   = tid & 63;     // FC element pair index

    __shared__ float  w_stage[20480];   // 80 KB: W staging (first 64 KB used);
                                        // also the 1-block/CU occupancy forcer
    __shared__ int    tok_l[T_];        // 4 KB
    __shared__ float4 hb4[2][H_ / 4];   // double-buffered h

    for (int s = tid; s < T_; s += 512) tok_l[s] = x[(size_t)b * T_ + s];
    if (tid < H_) ((float*)hb4[0])[tid] = 0.f;

    float fw0 = fcW[nw * 256 + dir * H_ + 2 * e];
    float fw1 = fcW[nw * 256 + dir * H_ + 2 * e + 1];

    const float* Whh = dir ? Whh_b : Whh_f;

    // Stage gate r (rows r*128..r*128+127, 64 KB) into LDS, read own chunk
    // into registers, then overwrite with gate r+1 (kills rematerialization).
    // Values are bit-identical to round 6's direct loads:
    // w4[r][k] = W_hh[r*128+j][ q*32 + ((k+2q)&7)*4 .. +4 )
    float4 w4[4][8];
    for (int r = 0; r < 4; ++r) {
        const float4* Wg4 = (const float4*)(Whh + (size_t)r * H_ * H_);
        float4* st4 = (float4*)w_stage;
        for (int idx = tid; idx < (H_ * H_) / 4; idx += 512) st4[idx] = Wg4[idx];
        __syncthreads();
        const float4* myrow = (const float4*)(w_stage + j * H_ + q * 32);
#pragma unroll
        for (int k = 0; k < 8; ++k) w4[r][k] = myrow[(k + 2 * q) & 7];
        __syncthreads();   // WAR: next round overwrites w_stage
    }
#pragma unroll
    for (int r = 0; r < 4; ++r)
#pragma unroll
        for (int k = 0; k < 8; ++k)
            asm volatile("" : "+v"(w4[r][k].x), "+v"(w4[r][k].y),
                              "+v"(w4[r][k].z), "+v"(w4[r][k].w));
    asm volatile("" : "+v"(fw0), "+v"(fw1));

    const float* projd = proj + (size_t)dir * (V_ * G_);
    int gown = q * H_ + j;          // own gate row in proj
    float c = 0.f;

    float pv_c = projd[tok_l[dir ? (T_ - 1) : 0] * G_ + gown];

    int cur = 0;
    for (int t = 0; t < T_; ++t) {
        int tt = dir ? (T_ - 1 - t) : t;
        int tn = (t + 1 < T_) ? (t + 1) : t;
        float pv_n = projd[tok_l[dir ? (T_ - 1 - tn) : tn] * G_ + gown];

        const float4* hb = (const float4*)hb4[cur];
        float a0 = 0.f, a1 = 0.f, a2 = 0.f, a3 = 0.f;
#pragma unroll
        for (int k = 0; k < 8; ++k) {
            float4 hv = hb[q * 8 + ((k + 2 * q) & 7)];
            float4 w0 = w4[0][k], w1 = w4[1][k], w2 = w4[2][k], w3 = w4[3][k];
            a0 += w0.x * hv.x; a0 += w0.y * hv.y; a0 += w0.z * hv.z; a0 += w0.w * hv.w;
            a1 += w1.x * hv.x; a1 += w1.y * hv.y; a1 += w1.z * hv.z; a1 += w1.w * hv.w;
            a2 += w2.x * hv.x; a2 += w2.y * hv.y; a2 += w2.z * hv.z; a2 += w2.w * hv.w;
            a3 += w3.x * hv.x; a3 += w3.y * hv.y; a3 += w3.z * hv.z; a3 += w3.w * hv.w;
        }
        // quad reduce via DPP (bit-identical to shfl_xor 1,2)
        a0 += dppf<QP_XOR1>(a0); a0 += dppf<QP_XOR2>(a0);
        a1 += dppf<QP_XOR1>(a1); a1 += dppf<QP_XOR2>(a1);
        a2 += dppf<QP_XOR1>(a2); a2 += dppf<QP_XOR2>(a2);
        a3 += dppf<QP_XOR1>(a3); a3 += dppf<QP_XOR2>(a3);

        float tot = (q == 0) ? a0 : (q == 1) ? a1 : (q == 2) ? a2 : a3;
        tot += pv_c;
        float act = (q == 2) ? tanhf(tot) : 1.f / (1.f + expf(-tot));

        // gather quad activations via DPP broadcasts
        float gi = dppf<QP_BC0>(act);
        float gf = dppf<QP_BC1>(act);
        float gg = dppf<QP_BC2>(act);
        float go = dppf<QP_BC3>(act);

        c = gf * c + gi * gg;
        float h = go * tanhf(c);
        if (q == 0) ((float*)hb4[cur ^ 1])[j] = h;
        __syncthreads();                   // single barrier per step

        // FC: wave nw computes logit nw; each lane dots 2 h elements
        float2 h2 = ((const float2*)hb4[cur ^ 1])[e];
        float p = fw0 * h2.x + fw1 * h2.y;
        p += dppf<QP_XOR1>(p);
        p += dppf<QP_XOR2>(p);
        p += swzf<SWZ_XOR4>(p);
        p += dppf<ROW_ROR8>(p);
        p += swzf<SWZ_XOR16>(p);
        float psum = p + __int_as_float(__builtin_amdgcn_readlane(__float_as_int(p), 32));
        if (e == 0) part[(((size_t)dir * T_ + tt) * B_ + b) * N_ + nw] = psum;

        pv_c = pv_n;
        cur ^= 1;
    }
}

// ---------------------------------------------------------------------------
// K2: Viterbi — round-3/6 alternating-layout version VERBATIM (passing).
// ---------------------------------------------------------------------------
__global__ __launch_bounds__(64) void viterbi_kernel(
    const float* __restrict__ part,   // [2][T][B][8]
    const float* __restrict__ fc_b,
    const float* __restrict__ start_t,
    const float* __restrict__ end_t,
    const float* __restrict__ trans,  // [8][8]
    int* __restrict__ out)            // [B][T]
{
    int b = blockIdx.x;
    int l = threadIdx.x;
    int lo = l & 7, hi = l >> 3;

    __shared__ unsigned int hist_l[T_];

    float trA  = trans[lo * 8 + hi];   // style A: i=lo, j=hi
    float trB  = trans[hi * 8 + lo];   // style B: i=hi, j=lo
    float fcbA = fc_b[hi];
    float fcbB = fc_b[lo];
    const float* pf = part;
    const float* pb = part + (size_t)T_ * B_ * N_;

#define TSEL(ov, oi) { if ((ov) > v || ((ov) == v && (oi) < idx)) { v = (ov); idx = (oi); } }

#define VSTEPA(emval, tcur) { \
    float v = (score + trA) + (emval); int idx = lo; \
    { float ov = dppf<QP_XOR1>(v); int oi = dppi<QP_XOR1>(idx); TSEL(ov, oi) } \
    { float ov = dppf<QP_XOR2>(v); int oi = dppi<QP_XOR2>(idx); TSEL(ov, oi) } \
    { float ov = swzf<SWZ_XOR4>(v); int oi = swzi<SWZ_XOR4>(idx); TSEL(ov, oi) } \
    score = v; \
    unsigned pk = 0; \
    _Pragma("unroll") \
    for (int jj = 0; jj < 8; ++jj) \
        pk |= (unsigned)(__builtin_amdgcn_readlane(idx, 8 * jj) & 7) << (3 * jj); \
    if (l == 0) hist_l[tcur] = pk; }

#define VSTEPB(emval, tcur) { \
    float v = (score + trB) + (emval); int idx = hi; \
    { float ov = dppf<ROW_ROR8>(v); int oi = dppi<ROW_ROR8>(idx); TSEL(ov, oi) } \
    { float ov = swzf<SWZ_XOR16>(v); int oi = swzi<SWZ_XOR16>(idx); TSEL(ov, oi) } \
    { float ov = __shfl_xor(v, 32); int oi = __shfl_xor(idx, 32); TSEL(ov, oi) } \
    score = v; \
    unsigned pk = 0; \
    _Pragma("unroll") \
    for (int jj = 0; jj < 8; ++jj) \
        pk |= (unsigned)(__builtin_amdgcn_readlane(idx, jj) & 7) << (3 * jj); \
    if (l == 0) hist_l[tcur] = pk; }

#define LOADSUB(dst, ss) { \
    int t0_ = (ss) * 8; \
    _Pragma("unroll") \
    for (int p = 0; p < 8; ++p) { \
        int t_ = t0_ + p; \
        int jsel = (p & 1) ? hi : lo; \
        float fcbs = (p & 1) ? fcbA : fcbB; \
        size_t base = ((size_t)t_ * B_ + b) * N_ + jsel; \
        dst[p] = (pf[base] + pb[base]) + fcbs; } }

#define PROC8(arr, t0_) { \
    VSTEPB(arr[0], (t0_) + 0) VSTEPA(arr[1], (t0_) + 1) \
    VSTEPB(arr[2], (t0_) + 2) VSTEPA(arr[3], (t0_) + 3) \
    VSTEPB(arr[4], (t0_) + 4) VSTEPA(arr[5], (t0_) + 5) \
    VSTEPB(arr[6], (t0_) + 6) VSTEPA(arr[7], (t0_) + 7) }

    float emA[8], emB[8];
    float score;

    LOADSUB(emA, 0)
    LOADSUB(emB, 1)
    score = start_t[lo] + emA[0];
    VSTEPA(emA[1], 1) VSTEPB(emA[2], 2) VSTEPA(emA[3], 3) VSTEPB(emA[4], 4)
    VSTEPA(emA[5], 5) VSTEPB(emA[6], 6) VSTEPA(emA[7], 7)

    for (int s = 1; s < 127; s += 2) {
        LOADSUB(emA, s + 1)
        PROC8(emB, s * 8)
        LOADSUB(emB, s + 2)
        PROC8(emA, (s + 1) * 8)
    }
    PROC8(emB, 127 * 8)

    score += end_t[hi];
    int tag;
    {
        float v = score; int idx = hi;
        { float ov = dppf<ROW_ROR8>(v); int oi = dppi<ROW_ROR8>(idx); TSEL(ov, oi) }
        { float ov = swzf<SWZ_XOR16>(v); int oi = swzi<SWZ_XOR16>(idx); TSEL(ov, oi) }
        { float ov = __shfl_xor(v, 32); int oi = __shfl_xor(idx, 32); TSEL(ov, oi) }
        tag = idx;
    }
    if (l == 0) out[(size_t)b * T_ + (T_ - 1)] = tag;
    __syncthreads();

    for (int t0b = T_ - 16; t0b >= 0; t0b -= 16) {
        unsigned int pk[16];
#pragma unroll
        for (int qq = 0; qq < 16; ++qq) pk[qq] = hist_l[t0b + qq];
#pragma unroll
        for (int qq = 15; qq >= 0; --qq) {
            int t = t0b + qq;
            if (t >= 1) {
                tag = (pk[qq] >> (3 * tag)) & 7;
                if (l == 0) out[(size_t)b * T_ + t - 1] = tag;
            }
        }
    }
#undef TSEL
#undef VSTEPA
#undef VSTEPB
#undef LOADSUB
#undef PROC8
}

extern "C" void kernel_launch(void* const* d_in, const int* in_sizes, int n_in,
                              void* d_out, int out_size, void* d_ws, size_t ws_size,
                              hipStream_t stream) {
    (void)in_sizes; (void)n_in; (void)out_size; (void)ws_size;
    const int*   x      = (const int*)  d_in[0];
    const float* emb    = (const float*)d_in[1];
    const float* Wih_f  = (const float*)d_in[2];
    const float* Whh_f  = (const float*)d_in[3];
    const float* b_f    = (const float*)d_in[4];
    const float* Wih_b  = (const float*)d_in[5];
    const float* Whh_b  = (const float*)d_in[6];
    const float* b_b    = (const float*)d_in[7];
    const float* fcW    = (const float*)d_in[8];
    const float* fcb    = (const float*)d_in[9];
    const float* startt = (const float*)d_in[10];
    const float* endt   = (const float*)d_in[11];
    const float* trans  = (const float*)d_in[12];

    float* proj = (float*)d_ws;                    // 2*32*512 floats = 128 KB
    float* part = proj + 2 * V_ * G_;              // 2*1024*64*8 floats = 4 MB
    int*   out  = (int*)d_out;

    proj_kernel<<<64, 512, 0, stream>>>(emb, Wih_f, b_f, Wih_b, b_b, proj);
    lstm_kernel<<<128, 512, 0, stream>>>(x, Whh_f, Whh_b, proj, fcW, part);
    viterbi_kernel<<<64, 64, 0, stream>>>(part, fcb, startt, endt, trans, out);
}